// Round 10
// baseline (276.222 us; speedup 1.0000x reference)
//
#include <hip/hip_runtime.h>
#include <hip/hip_bf16.h>
#include <math.h>

// Problem constants (fixed by setup_inputs)
#define BB 16
#define TT 8192
#define DD 256
#define MAXSEG 4096   // max possible segments per row (alternating pattern)
#define RPB 8         // segment rows per tile
#define LN_EPS 1e-5f

typedef float vfloat4 __attribute__((ext_vector_type(4)));  // nontemporal-safe

// ---------------------------------------------------------------------------
// Setup kernel (merged): blocks [0,BB) run the per-batch-row segment scan;
// blocks [BB, BB+64) transpose W (4 rows each); block BB+64 computes
// LN(b_proj) with a single wave. 1024 threads each.
__global__ __launch_bounds__(1024) void setup_kernel(
    const int* __restrict__ ids, const float* __restrict__ W,
    const float* __restrict__ bp, const float* __restrict__ gamma,
    const float* __restrict__ beta, int* __restrict__ counts,
    int* __restrict__ seg_start, int* __restrict__ nseg_g,
    float* __restrict__ mask_out, float* __restrict__ Wt,
    float* __restrict__ ln_empty) {
    __shared__ int wtot_s[16];
    __shared__ int wtot_n[16];
    __shared__ int segs[MAXSEG];
    __shared__ int pvals[MAXSEG];

    int tid = threadIdx.x;
    int lane = tid & 63;
    int wv = tid >> 6;

    if (blockIdx.x >= BB) {
        int bi = blockIdx.x - BB;
        if (bi < 64) {  // transpose: 4 d-rows per block
            int d = bi * 4 + (tid >> 8);
            int e = tid & 255;
            Wt[d * DD + e] = W[e * DD + d];
        } else if (wv == 0) {  // LN of b_proj, one wave
            int e0 = lane * 4;
            float4 v = *(const float4*)(bp + e0);
            float s = v.x + v.y + v.z + v.w;
            float sq = v.x * v.x + v.y * v.y + v.z * v.z + v.w * v.w;
#pragma unroll
            for (int o = 32; o > 0; o >>= 1) {
                s += __shfl_down(s, o);
                sq += __shfl_down(sq, o);
            }
            s = __shfl(s, 0);
            sq = __shfl(sq, 0);
            float mu = s * (1.f / (float)DD);
            float var = sq * (1.f / (float)DD) - mu * mu;
            float rs = rsqrtf(fmaxf(var, 0.f) + LN_EPS);
            float4 ge = *(const float4*)(gamma + e0);
            float4 be = *(const float4*)(beta + e0);
            float4 o4;
            o4.x = (v.x - mu) * rs * ge.x + be.x;
            o4.y = (v.y - mu) * rs * ge.y + be.y;
            o4.z = (v.z - mu) * rs * ge.z + be.z;
            o4.w = (v.w - mu) * rs * ge.w + be.w;
            *(float4*)(ln_empty + e0) = o4;
        }
        return;
    }

    // ---- segment scan, one block per batch row
    const int TPT = 8;  // tokens per thread
    int b = blockIdx.x;
    const int* row = ids + b * TT;
    int t0 = tid * TPT;

    int4 q0 = ((const int4*)(row + t0))[0];
    int4 q1 = ((const int4*)(row + t0))[1];
    int v[TPT] = {q0.x, q0.y, q0.z, q0.w, q1.x, q1.y, q1.z, q1.w};
    int prev = (tid == 0) ? 0 : row[t0 - 1];  // 0 == boundary

    bool nb[TPT], st[TPT];
    int cstart = 0, cnon = 0;
#pragma unroll
    for (int j = 0; j < TPT; ++j) {
        nb[j] = (v[j] != 0);
        int pv = (j == 0) ? prev : v[j - 1];
        st[j] = nb[j] && (pv == 0);
        cstart += st[j] ? 1 : 0;
        cnon += nb[j] ? 1 : 0;
    }

    int ss = cstart, sn = cnon;
#pragma unroll
    for (int o = 1; o < 64; o <<= 1) {
        int us = __shfl_up(ss, o);
        int un = __shfl_up(sn, o);
        if (lane >= o) { ss += us; sn += un; }
    }
    if (lane == 63) { wtot_s[wv] = ss; wtot_n[wv] = sn; }
    __syncthreads();

    int bs = 0, bn = 0, tot_s = 0, tot_n = 0;
#pragma unroll
    for (int j = 0; j < 16; ++j) {
        int a = wtot_s[j], c = wtot_n[j];
        if (j < wv) { bs += a; bn += c; }
        tot_s += a; tot_n += c;
    }
    bs += ss - cstart;  // exclusive prefix
    bn += sn - cnon;

#pragma unroll
    for (int j = 0; j < TPT; ++j) {
        if (st[j]) { segs[bs] = t0 + j; pvals[bs] = bn; bs++; }
        bn += nb[j] ? 1 : 0;
    }
    __syncthreads();

    int ns = tot_s;
    for (int w = tid; w < TT; w += 1024) {
        int c = 0;
        if (w < ns) {
            int pe = (w + 1 < ns) ? pvals[w + 1] : tot_n;
            c = pe - pvals[w];
            seg_start[b * TT + w] = segs[w];
        }
        counts[b * TT + w] = c;
        mask_out[b * TT + w] = (w < ns) ? 1.0f : 0.0f;
    }
    if (tid == 0) nseg_g[b] = ns;
}

// ---------------------------------------------------------------------------
// Pool kernel: one wave per segment w; 8 independent accumulators + fully
// predicated 7-load tail (R9-proven). Writes pooled[b][w][256] to global
// workspace; rows [ns, ceil(ns/8)*8) get zeros so the gemm tile tail computes
// exactly LN(b_proj) with no guards.
__global__ __launch_bounds__(256) void pool_kernel(
    const float* __restrict__ x, const int* __restrict__ counts,
    const int* __restrict__ seg_start, const int* __restrict__ nseg,
    float* __restrict__ pooled) {
    int b = blockIdx.x;
    int ns = nseg[b];
    int ns8 = (ns + 7) & ~7;
    int lane = threadIdx.x & 63;
    int wv = threadIdx.x >> 6;
    int w = blockIdx.y * 4 + wv;
    if (w >= ns8) return;

    vfloat4 r = {0.f, 0.f, 0.f, 0.f};
    if (w < ns) {
        int s = seg_start[b * TT + w];
        int len = counts[b * TT + w];
        const vfloat4* xp = (const vfloat4*)(x + ((size_t)(b * TT + s)) * DD) + lane;
        vfloat4 a[8];
#pragma unroll
        for (int j = 0; j < 8; ++j) a[j] = (vfloat4){0.f, 0.f, 0.f, 0.f};
        int t = 0;
        for (; t + 8 <= len; t += 8) {
#pragma unroll
            for (int j = 0; j < 8; ++j)
                a[j] += __builtin_nontemporal_load(xp + (t + j) * 64);
        }
#pragma unroll
        for (int j = 0; j < 7; ++j)
            if (t + j < len)
                a[j] += __builtin_nontemporal_load(xp + (t + j) * 64);
        r = ((a[0] + a[1]) + (a[2] + a[3])) + ((a[4] + a[5]) + (a[6] + a[7]));
        r *= (1.f / (float)len);
    }
    *(vfloat4*)(pooled + ((size_t)(b * MAXSEG + w)) * DD + 4 * lane) = r;
}

// ---------------------------------------------------------------------------
// GEMM + LN + fill. Work tiles read pooled via WAVE-UNIFORM addresses ->
// scalar K$ loads (s_load_dwordx4), so the FMA loop is v_fmac(acc, s_p, v_w)
// with ZERO LDS traffic (the R9 kernel issued 512 ds_read_b128 broadcasts per
// wave - the suspected hidden bottleneck). Safe because pooled was written by
// a previous kernel (K$ coherent at dispatch boundaries only).
__global__ __launch_bounds__(256) void gemm_fill(
    const float* __restrict__ pooled, const float* __restrict__ Wt,
    const float* __restrict__ bp, const float* __restrict__ gamma,
    const float* __restrict__ beta, const int* __restrict__ nseg,
    const float* __restrict__ ln_e, float* __restrict__ out) {
    __shared__ float red[4][RPB][2];

    int b = blockIdx.x;
    int wbase = blockIdx.y * RPB;
    int ns = nseg[b];
    int tid = threadIdx.x;
    int lane = tid & 63;
    int wv = tid >> 6;
    size_t rowbase = ((size_t)(b * TT + wbase)) * DD;

    if (wbase >= ns) {  // pure fill tile: 8 rows of LN(b_proj)
        vfloat4 lv = *(const vfloat4*)(ln_e + 4 * lane);
        float* o = out + rowbase + 4 * lane;
#pragma unroll
        for (int rr = 0; rr < 2; ++rr) {
            int row = wv * 2 + rr;
            __builtin_nontemporal_store(lv, (vfloat4*)(o + (size_t)row * DD));
        }
        return;
    }

    // ---- GEMM: acc[r] = bp[c] + sum_d pooled[r][d] * Wt[d][c]
    const float* P = pooled + ((size_t)(b * MAXSEG + wbase)) * DD;  // 8 x 256
    int c = wv * 64 + lane;
    float acc[RPB];
    float bias = bp[c];
#pragma unroll
    for (int r = 0; r < RPB; ++r) acc[r] = bias;

    const float* Wc = Wt + c;
    float w0 = Wc[0 * DD];
    float w1 = Wc[1 * DD];
    float w2 = Wc[2 * DD];
    float w3 = Wc[3 * DD];
    float4 p[RPB];
#pragma unroll
    for (int r = 0; r < RPB; ++r) p[r] = *(const float4*)(P + r * DD);  // uniform -> s_load

#pragma unroll 1
    for (int d0 = 0; d0 < DD; d0 += 4) {
        int dn = (d0 + 4) & 255;  // wraps harmlessly on last iter
        float n0 = Wc[(dn + 0) * DD];
        float n1 = Wc[(dn + 1) * DD];
        float n2 = Wc[(dn + 2) * DD];
        float n3 = Wc[(dn + 3) * DD];
        float4 np[RPB];
#pragma unroll
        for (int r = 0; r < RPB; ++r) np[r] = *(const float4*)(P + r * DD + dn);
#pragma unroll
        for (int r = 0; r < RPB; ++r) {
            acc[r] = fmaf(p[r].x, w0, acc[r]);
            acc[r] = fmaf(p[r].y, w1, acc[r]);
            acc[r] = fmaf(p[r].z, w2, acc[r]);
            acc[r] = fmaf(p[r].w, w3, acc[r]);
        }
        w0 = n0; w1 = n1; w2 = n2; w3 = n3;
#pragma unroll
        for (int r = 0; r < RPB; ++r) p[r] = np[r];
    }

    // ---- LN: wave-partials over 64 cols, combined across 4 waves via LDS.
    // Zero-padded rows give acc == bias -> exactly LN(b_proj).
#pragma unroll
    for (int r = 0; r < RPB; ++r) {
        float s = acc[r];
        float sq = acc[r] * acc[r];
#pragma unroll
        for (int o = 32; o > 0; o >>= 1) {
            s += __shfl_down(s, o);
            sq += __shfl_down(sq, o);
        }
        if (lane == 0) { red[wv][r][0] = s; red[wv][r][1] = sq; }
    }
    __syncthreads();

    float ga = gamma[c], be = beta[c];
#pragma unroll
    for (int r = 0; r < RPB; ++r) {
        float s = red[0][r][0] + red[1][r][0] + red[2][r][0] + red[3][r][0];
        float sq = red[0][r][1] + red[1][r][1] + red[2][r][1] + red[3][r][1];
        float mu = s * (1.f / (float)DD);
        float var = sq * (1.f / (float)DD) - mu * mu;
        float rs = rsqrtf(fmaxf(var, 0.f) + LN_EPS);
        float v = (acc[r] - mu) * rs * ga + be;
        __builtin_nontemporal_store(v, out + rowbase + (size_t)r * DD + c);
    }
}

// ---------------------------------------------------------------------------
extern "C" void kernel_launch(void* const* d_in, const int* in_sizes, int n_in,
                              void* d_out, int out_size, void* d_ws, size_t ws_size,
                              hipStream_t stream) {
    const float* x = (const float*)d_in[0];
    const int* ids = (const int*)d_in[1];
    const float* W = (const float*)d_in[2];
    const float* bp = (const float*)d_in[3];
    const float* gamma = (const float*)d_in[4];
    const float* beta = (const float*)d_in[5];

    float* out = (float*)d_out;                       // [B, T, D]
    float* mask = out + (size_t)BB * TT * DD;         // [B, T]

    // workspace layout
    char* ws = (char*)d_ws;
    int* counts = (int*)ws;                                    // B*T ints
    int* seg_start = (int*)(ws + (size_t)BB * TT * 4);         // B*T ints
    int* nseg = (int*)(ws + (size_t)2 * BB * TT * 4);          // B ints
    float* Wt = (float*)(ws + (size_t)2 * BB * TT * 4 + 256);  // D*D floats
    float* ln_e = Wt + DD * DD;                                // D floats
    float* pooled = ln_e + DD;                                 // B*MAXSEG*D floats (64 MB)

    hipLaunchKernelGGL(setup_kernel, dim3(BB + 64 + 1), dim3(1024), 0, stream,
                       ids, W, bp, gamma, beta, counts, seg_start, nseg, mask,
                       Wt, ln_e);
    hipLaunchKernelGGL(pool_kernel, dim3(BB, MAXSEG / 4), dim3(256), 0, stream,
                       x, counts, seg_start, nseg, pooled);
    hipLaunchKernelGGL(gemm_fill, dim3(BB, TT / RPB), dim3(256), 0, stream,
                       pooled, Wt, bp, gamma, beta, nseg, ln_e, out);
}